// Round 6
// baseline (241.879 us; speedup 1.0000x reference)
//
#include <hip/hip_runtime.h>
#include <math.h>

#define B_  2
#define S_  2048
#define D_  1024
#define H_  16
#define DK_ 64
#define NT_ (S_ / 64)   // 32 key tiles

typedef unsigned short u16;
typedef unsigned int u32;
typedef __bf16 bf16x8 __attribute__((ext_vector_type(8)));
typedef float f32x4 __attribute__((ext_vector_type(4)));

typedef const __attribute__((address_space(1))) void* gas1_t;
typedef __attribute__((address_space(3))) void* las3_t;

__device__ __forceinline__ void gload_lds16(const void* g, void* l) {
    // async global->LDS, 16B per lane; LDS dst = wave-uniform base + lane*16
    __builtin_amdgcn_global_load_lds((gas1_t)g, (las3_t)l, 16, 0, 0);
}

__device__ __forceinline__ u16 f2bf(float f) {
    union { float f; unsigned u; } v; v.f = f;
    return (u16)((v.u + 0x7fffu + ((v.u >> 16) & 1u)) >> 16);   // RNE
}

// pack two f32 into two bf16 (round-half-up) in one u32: [lo | hi<<16]
__device__ __forceinline__ u32 pack_bf16_2(float lo, float hi) {
    union { float f; u32 u; } a, b;
    a.f = lo; b.f = hi;
    return __builtin_amdgcn_perm(b.u + 0x8000u, a.u + 0x8000u, 0x07060302u);
}

// ---------------------------------------------------------------------------
// Fused fp32 -> bf16 cast over all 7 tensors + mask -> f32 factor (1 / 0)
// + per-batch masked-key count (softmax denominator correction).
// ---------------------------------------------------------------------------
__global__ __launch_bounds__(256)
void cast_all(const float* __restrict__ q, const float* __restrict__ k,
              const float* __restrict__ v, const float* __restrict__ wq,
              const float* __restrict__ wk, const float* __restrict__ wv,
              const float* __restrict__ wo, const int* __restrict__ mask,
              u16* __restrict__ qb, u16* __restrict__ kb, u16* __restrict__ vb,
              u16* __restrict__ wqb, u16* __restrict__ wkb, u16* __restrict__ wvb,
              u16* __restrict__ wob, float* __restrict__ mfac,
              float* __restrict__ nmaskf)
{
    const int bi = blockIdx.x;
    const int tid = threadIdx.x;
    if (bi >= 16400) {                 // masked-key count for batch b
        const int b = bi - 16400;
        __shared__ int red[256];
        int c = 0;
#pragma unroll
        for (int j = 0; j < 8; ++j)
            c += (mask[b * S_ + tid * 8 + j] == 0) ? 1 : 0;
        red[tid] = c;
        __syncthreads();
        for (int s = 128; s > 0; s >>= 1) {
            if (tid < s) red[tid] += red[tid + s];
            __syncthreads();
        }
        if (tid == 0) nmaskf[b] = (float)red[0];
        return;
    }
    if (bi >= 16384) {                 // mask -> float factor
        const int idx = (bi - 16384) * 256 + tid;
        mfac[idx] = mask[idx] ? 1.0f : 0.0f;
        return;
    }
    const int i = bi * 256 + tid;      // float4 index
    const float* src; u16* dst; int off;
    if (i < 3 * 1048576) {
        const int seg = i >> 20; off = i & 1048575;
        src = (seg == 0) ? q : (seg == 1) ? k : v;
        dst = (seg == 0) ? qb : (seg == 1) ? kb : vb;
    } else {
        const int j = i - 3 * 1048576;
        const int seg = j >> 18; off = j & 262143;
        src = (seg == 0) ? wq : (seg == 1) ? wk : (seg == 2) ? wv : wo;
        dst = (seg == 0) ? wqb : (seg == 1) ? wkb : (seg == 2) ? wvb : wob;
    }
    const float4 val = ((const float4*)src)[off];
    uint2 o;
    o.x = pack_bf16_2(val.x, val.y);
    o.y = pack_bf16_2(val.z, val.w);
    ((uint2*)dst)[off] = o;
}

// ---------------------------------------------------------------------------
// bf16 NT GEMM, BK=64, XOR-swizzled LDS (16B chunks, chunk ^= row&7).
// mode 0: fp32 out[m*D+n], bias[n]
// mode 1: bf16 out[((b*H+h)*S+s)*DK+dk] (split heads), bias[n], *scale,
//         optionally * rowfac[m]   (K projection: zero masked key rows)
// mode 3: bf16 out[m*4096+n], bias[m], optionally * colfac[n]  (V^T)
// ---------------------------------------------------------------------------
template<int BN>
__device__ __forceinline__ void gemm_body(
    const u16* __restrict__ A, const u16* __restrict__ W,
    const float* __restrict__ bias, void* __restrict__ outp,
    float scale, int mode, int m0, int n0,
    const float* __restrict__ rowfac, const float* __restrict__ colfac)
{
    constexpr int NJ = BN / 32;
    __shared__ u16 sA[128 * 64];      // 16 KB
    __shared__ u16 sW[BN * 64];       // 16 or 8 KB

    const int tid  = threadIdx.x;
    const int wave = tid >> 6, lane = tid & 63;
    const int quad = lane >> 4, l16 = lane & 15;
    const int wm = (wave >> 1) * 64;
    const int wn = (wave & 1) * (BN / 2);
    const int srow = lane >> 3;                 // row within 8-row staging group
    const int scol = ((lane & 7) ^ srow) * 8;   // swizzled source column (u16)
    const int sw7  = l16 & 7;

    f32x4 acc[4][NJ];
    const f32x4 zero = {0.f, 0.f, 0.f, 0.f};
#pragma unroll
    for (int i = 0; i < 4; ++i)
#pragma unroll
        for (int j = 0; j < NJ; ++j) acc[i][j] = zero;

    const u16* ast = A + (size_t)(m0 + wave * 8 + srow) * D_ + scol;
    const u16* wst = W + (size_t)(n0 + wave * 8 + srow) * D_ + scol;

    for (int k0 = 0; k0 < D_; k0 += 64) {
#pragma unroll
        for (int t = 0; t < 4; ++t)
            gload_lds16(ast + (size_t)t * 32 * D_ + k0, sA + (wave + t * 4) * 512);
        if (BN == 128) {
#pragma unroll
            for (int t = 0; t < 4; ++t)
                gload_lds16(wst + (size_t)t * 32 * D_ + k0, sW + (wave + t * 4) * 512);
        } else {
#pragma unroll
            for (int t = 0; t < 2; ++t)
                gload_lds16(wst + (size_t)t * 32 * D_ + k0, sW + (wave + t * 4) * 512);
        }
        __syncthreads();

#pragma unroll
        for (int kh = 0; kh < 2; ++kh) {
            const int phys = ((kh * 4 + quad) ^ sw7) * 8;
            bf16x8 af[4], bfr[NJ];
#pragma unroll
            for (int i = 0; i < 4; ++i)
                af[i] = *(const bf16x8*)(sA + (wm + i * 16 + l16) * 64 + phys);
#pragma unroll
            for (int j = 0; j < NJ; ++j)
                bfr[j] = *(const bf16x8*)(sW + (wn + j * 16 + l16) * 64 + phys);
#pragma unroll
            for (int i = 0; i < 4; ++i)
#pragma unroll
                for (int j = 0; j < NJ; ++j)
                    acc[i][j] = __builtin_amdgcn_mfma_f32_16x16x32_bf16(af[i], bfr[j], acc[i][j], 0, 0, 0);
        }
        __syncthreads();
    }

    // Epilogue. C frag: row = quad*4+reg, col = lane&15
#pragma unroll
    for (int i = 0; i < 4; ++i) {
        float rf4[4];
        if (mode == 1 && rowfac) {
#pragma unroll
            for (int r = 0; r < 4; ++r)
                rf4[r] = rowfac[m0 + wm + i * 16 + quad * 4 + r];
        }
#pragma unroll
        for (int j = 0; j < NJ; ++j) {
            const int n = n0 + wn + j * 16 + l16;
            if (mode == 3) {
                const float cf = colfac ? colfac[n] : 1.0f;
#pragma unroll
                for (int r = 0; r < 4; ++r) {
                    const int mp = m0 + wm + i * 16 + quad * 4 + r;
                    ((u16*)outp)[(size_t)mp * (B_ * S_) + n] = f2bf((acc[i][j][r] + bias[mp]) * cf);
                }
            } else {
                const float bn = bias[n];
#pragma unroll
                for (int r = 0; r < 4; ++r) {
                    const int m = m0 + wm + i * 16 + quad * 4 + r;
                    float v = acc[i][j][r] + bn;
                    if (mode == 0) {
                        ((float*)outp)[(size_t)m * D_ + n] = v;
                    } else {
                        v *= scale;
                        if (rowfac) v *= rf4[r];
                        const int b = m >> 11, s = m & (S_ - 1);
                        const int h = n >> 6, dk = n & 63;
                        ((u16*)outp)[(((size_t)(b * H_ + h)) * S_ + s) * DK_ + dk] = f2bf(v);
                    }
                }
            }
        }
    }
}

__global__ __launch_bounds__(256)
void qkv_gemm(const u16* __restrict__ qin, const u16* __restrict__ kin, const u16* __restrict__ vin,
              const u16* __restrict__ wqb, const u16* __restrict__ wkb, const u16* __restrict__ wvb,
              const float* __restrict__ bq, const float* __restrict__ bk, const float* __restrict__ bv,
              u16* __restrict__ Qp, u16* __restrict__ Kp, u16* __restrict__ Vt,
              const float* __restrict__ mfac)
{
    const int z = blockIdx.z;
    if (z == 2) {
        // V^T = Wv . value^T ; zero masked key columns via colfac
        gemm_body<128>(wvb, vin, bv, Vt, 1.0f, 3, blockIdx.x * 128, blockIdx.y * 128,
                       nullptr, mfac);
    } else {
        const u16* A = (z == 0) ? qin : kin;
        const u16* W = (z == 0) ? wqb : wkb;
        const float* bias = (z == 0) ? bq : bk;
        u16* outp = (z == 0) ? Qp : Kp;
        // Q pre-scaled by log2(e)/sqrt(DK); K rows zeroed where masked
        const float scale = (z == 0) ? 0.18033688011112042f : 1.0f;
        const float* rf = (z == 1) ? mfac : nullptr;
        gemm_body<128>(A, W, bias, outp, scale, 1, blockIdx.y * 128, blockIdx.x * 128,
                       rf, nullptr);
    }
}

__global__ __launch_bounds__(256)
void out_gemm(const u16* __restrict__ Xc, const u16* __restrict__ wob,
              const float* __restrict__ bo, float* __restrict__ out)
{
    gemm_body<64>(Xc, wob, bo, out, 1.0f, 0, blockIdx.y * 128, blockIdx.x * 64,
                  nullptr, nullptr);
}

// ---------------------------------------------------------------------------
// MFMA flash attention, software-pipelined: iter kt runs PV(kt-1) and QK(kt)
// as independent MFMA streams, then exp2(kt) -> P[kt&1]. P double-buffered
// (wave-private, no barrier); K double-, V triple-buffered so the DMA for
// tile kt+1 (issued right after the single per-iter barrier) never collides
// with PV(kt-1)'s V reads. Maskless: masked keys pre-zeroed in K and V^T;
// denominator = (P x ones via MFMA) - nmask. One barrier per iter.
// ---------------------------------------------------------------------------
__global__ __launch_bounds__(256)
void attn_mfma(const u16* __restrict__ Qp, const u16* __restrict__ Kp,
               const u16* __restrict__ Vt, const float* __restrict__ nmaskf,
               u16* __restrict__ Xc)
{
    __shared__ u16 sQP[128 * 64];     // 16 KB: Q staging, then P buf 0
    __shared__ u16 sP1[128 * 64];     // 16 KB: P buf 1
    __shared__ u16 sK[2][64 * 64];    // 16 KB double-buffered
    __shared__ u16 sV[3][64 * 64];    // 24 KB triple-buffered

    const int tid  = threadIdx.x;
    const int wave = tid >> 6, lane = tid & 63;
    const int quad = lane >> 4, l16 = lane & 15;
    const int qt = blockIdx.x & 15;
    const int bh = blockIdx.x >> 4;
    const int b  = bh >> 4;
    const int h  = bh & 15;
    const int srow = lane >> 3;                  // staging row within 8-row group
    const int scol = ((lane & 7) ^ srow) * 8;    // swizzled source column (u16)
    const int sw7  = l16 & 7;                    // row&7 for fragment reads

    const u16* Qb = Qp + ((size_t)bh * S_ + qt * 128) * DK_;
    const u16* Kb = Kp + (size_t)bh * S_ * DK_;
    const u16* Vb = Vt + ((size_t)h * 64) * (B_ * S_) + b * S_;

    // stage Q tile + K/V tiles 0 (swizzled)
#pragma unroll
    for (int t = 0; t < 4; ++t)
        gload_lds16(Qb + (size_t)((wave + t * 4) * 8 + srow) * DK_ + scol,
                    sQP + (wave + t * 4) * 512);
#pragma unroll
    for (int t = 0; t < 2; ++t) {
        const int tt = wave + t * 4;
        gload_lds16(Kb + (size_t)(tt * 8 + srow) * DK_ + scol, &sK[0][tt * 512]);
        gload_lds16(Vb + (size_t)(tt * 8 + srow) * (B_ * S_) + scol, &sV[0][tt * 512]);
    }
    __syncthreads();

    // issue K/V tile 1 DMA immediately (drained by the loop's first barrier)
#pragma unroll
    for (int t = 0; t < 2; ++t) {
        const int tt = wave + t * 4;
        gload_lds16(Kb + (size_t)(64 + tt * 8 + srow) * DK_ + scol, &sK[1][tt * 512]);
        gload_lds16(Vb + (size_t)(tt * 8 + srow) * (B_ * S_) + 64 + scol, &sV[1][tt * 512]);
    }

    // preload Q as B-frags: B[n=q=l16][k=quad*8+j], wave-private rows
    bf16x8 qf[2][2];
#pragma unroll
    for (int iq = 0; iq < 2; ++iq)
#pragma unroll
        for (int ks = 0; ks < 2; ++ks) {
            const int row = wave * 32 + iq * 16 + l16;
            const int phys = (ks * 4 + quad) ^ sw7;
            qf[iq][ks] = *(const bf16x8*)(sQP + row * 64 + phys * 8);
        }
    // wave w's qf rows are exactly bytes [4096w, 4096(w+1)) of sQP = its own
    // P-buf-0 slice -> overlay is wave-private, no barrier needed.
    u16* sPa = sQP + wave * 2048;   // P buf 0 (32x64)
    u16* sPb = sP1 + wave * 2048;   // P buf 1

    bf16x8 vones;
#pragma unroll
    for (int j = 0; j < 8; ++j) vones[j] = (__bf16)1.0f;

    f32x4 oacc[2][4];              // [im(q)][nd(d)]
    const f32x4 zero = {0.f, 0.f, 0.f, 0.f};
#pragma unroll
    for (int im = 0; im < 2; ++im)
#pragma unroll
        for (int nd = 0; nd < 4; ++nd) oacc[im][nd] = zero;
    f32x4 lfrag[2] = {zero, zero}; // lsum in C-layout: row q = quad*4+r

    f32x4 sfr[2][4];

    auto QK = [&](const u16* kbuf) {
        const int p0 = (quad ^ sw7) * 8;
        const int p1 = ((4 + quad) ^ sw7) * 8;
#pragma unroll
        for (int in = 0; in < 4; ++in) {
            const bf16x8 kf0 = *(const bf16x8*)(kbuf + (in * 16 + l16) * 64 + p0);
            const bf16x8 kf1 = *(const bf16x8*)(kbuf + (in * 16 + l16) * 64 + p1);
#pragma unroll
            for (int iq = 0; iq < 2; ++iq) {
                f32x4 t = __builtin_amdgcn_mfma_f32_16x16x32_bf16(kf0, qf[iq][0], zero, 0, 0, 0);
                sfr[iq][in] = __builtin_amdgcn_mfma_f32_16x16x32_bf16(kf1, qf[iq][1], t, 0, 0, 0);
            }
        }
    };
    auto EXPP = [&](u16* sPw) {
#pragma unroll
        for (int iq = 0; iq < 2; ++iq) {
#pragma unroll
            for (int in = 0; in < 4; ++in) {
                const float p0 = __builtin_amdgcn_exp2f(sfr[iq][in][0]);
                const float p1 = __builtin_amdgcn_exp2f(sfr[iq][in][1]);
                const float p2 = __builtin_amdgcn_exp2f(sfr[iq][in][2]);
                const float p3 = __builtin_amdgcn_exp2f(sfr[iq][in][3]);
                uint2 o;
                o.x = pack_bf16_2(p0, p1);
                o.y = pack_bf16_2(p2, p3);
                // P[q][k]: q=iq*16+l16, k=in*16+quad*4+r ; chunk=(k>>3)^(q&7)
                const int pchunk = (in * 2 + (quad >> 1)) ^ sw7;
                *(uint2*)(sPw + (iq * 16 + l16) * 64 + pchunk * 8 + (quad & 1) * 4) = o;
            }
        }
    };
    auto PV = [&](const u16* vbuf, const u16* sPw) {
#pragma unroll
        for (int ks = 0; ks < 2; ++ks) {
            const int phys = ((ks * 4 + quad) ^ sw7) * 8;
            bf16x8 pf[2];
#pragma unroll
            for (int im = 0; im < 2; ++im)
                pf[im] = *(const bf16x8*)(sPw + (im * 16 + l16) * 64 + phys);
#pragma unroll
            for (int im = 0; im < 2; ++im)
                lfrag[im] = __builtin_amdgcn_mfma_f32_16x16x32_bf16(pf[im], vones, lfrag[im], 0, 0, 0);
#pragma unroll
            for (int nd = 0; nd < 4; ++nd) {
                const bf16x8 vf = *(const bf16x8*)(vbuf + (nd * 16 + l16) * 64 + phys);
#pragma unroll
                for (int im = 0; im < 2; ++im)
                    oacc[im][nd] = __builtin_amdgcn_mfma_f32_16x16x32_bf16(pf[im], vf, oacc[im][nd], 0, 0, 0);
            }
        }
    };

    // peel kt=0: QK + exp2 (no PV yet); sK[0]/sV[0] already drained
    QK(&sK[0][0]);
    EXPP(sPa);

    // staging pointers for tile kt+1 (first in-loop stage = tile 2)
    const u16* kpre = Kb + (size_t)(2 * 64 + wave * 8 + srow) * DK_ + scol;
    const u16* vpre = Vb + (size_t)(wave * 8 + srow) * (B_ * S_) + 2 * 64 + scol;

    int kr = 1;          // K buf holding tile kt
    int vr = 0;          // V buf holding tile kt-1
    int vw = 2;          // V buf to receive tile kt+1

    for (int kt = 1; kt < NT_; ++kt) {
        __syncthreads();            // tile kt's DMA drained; all reads of the
                                    // buffers being re-staged are complete
        if (kt < NT_ - 1) {
            u16* kdst = &sK[kr ^ 1][wave * 512];
            u16* vdst = &sV[vw][wave * 512];
            gload_lds16(kpre, kdst);
            gload_lds16(kpre + (size_t)32 * DK_, kdst + 4 * 512);
            gload_lds16(vpre, vdst);
            gload_lds16(vpre + (size_t)32 * (B_ * S_), vdst + 4 * 512);
            kpre += (size_t)64 * DK_;
            vpre += 64;
        }

        u16* sPrd = (kt & 1) ? sPa : sPb;   // P written last iter
        u16* sPwr = (kt & 1) ? sPb : sPa;

        PV(&sV[vr][0], sPrd);   // tile kt-1   (independent MFMA stream)
        QK(&sK[kr][0]);         // tile kt     (independent MFMA stream)
        EXPP(sPwr);             // exp2 + pack P for next iter's PV

        kr ^= 1;
        vr = (vr == 2) ? 0 : vr + 1;
        vw = (vw == 2) ? 0 : vw + 1;
    }
    // drain: PV for the last tile (P in sPb since NT_-1 is odd; V buf = vr)
    PV(&sV[vr][0], sPb);

    // denominator: lfrag rows hold full row sums; subtract masked-key count
    // (each masked key contributed exp2(0)=1).
    const float nm = nmaskf[b];
    float linv[2][4];
#pragma unroll
    for (int im = 0; im < 2; ++im)
#pragma unroll
        for (int r = 0; r < 4; ++r)
            linv[im][r] = __builtin_amdgcn_rcpf(lfrag[im][r] - nm);

    // write O (merge-heads) bf16
#pragma unroll
    for (int im = 0; im < 2; ++im)
#pragma unroll
        for (int r = 0; r < 4; ++r) {
            const int s = qt * 128 + wave * 32 + im * 16 + quad * 4 + r;
            const float inv = linv[im][r];
#pragma unroll
            for (int nd = 0; nd < 4; ++nd)
                Xc[((size_t)(b * S_ + s)) * D_ + h * 64 + nd * 16 + l16] =
                    f2bf(oacc[im][nd][r] * inv);
        }
}

// ---------------------------------------------------------------------------
extern "C" void kernel_launch(void* const* d_in, const int* in_sizes, int n_in,
                              void* d_out, int out_size, void* d_ws, size_t ws_size,
                              hipStream_t stream)
{
    (void)in_sizes; (void)n_in; (void)out_size; (void)ws_size;

    const float* query = (const float*)d_in[0];
    const float* key   = (const float*)d_in[1];
    const float* value = (const float*)d_in[2];
    const int*   mask  = (const int*)d_in[3];
    const float* wq    = (const float*)d_in[4];
    const float* bq    = (const float*)d_in[5];
    const float* wk    = (const float*)d_in[6];
    const float* bk    = (const float*)d_in[7];
    const float* wv    = (const float*)d_in[8];
    const float* bv    = (const float*)d_in[9];
    const float* wo    = (const float*)d_in[10];
    const float* bo    = (const float*)d_in[11];

    const size_t NE = (size_t)B_ * S_ * D_;   // 4,194,304
    const size_t WE = (size_t)D_ * D_;        // 1,048,576

    u16* qb  = (u16*)d_ws;      // bf16 inputs
    u16* kb  = qb + NE;
    u16* vb  = kb + NE;
    u16* wqb = vb + NE;         // bf16 weights
    u16* wkb = wqb + WE;
    u16* wvb = wkb + WE;
    u16* wob = wvb + WE;
    u16* Qp  = wob + WE;        // projected heads
    u16* Kp  = Qp + NE;
    u16* Vt  = Kp + NE;         // V transposed: [h*64+dk][b*2048+s]
    float* mfac   = (float*)(Vt + NE);   // 4096 f32 mask factors (1/0)
    float* nmaskf = mfac + 4096;         // 2 f32 masked-key counts
    u16* Xc  = qb;              // alias: qb is dead after qkv_gemm

    cast_all<<<16402, 256, 0, stream>>>(query, key, value, wq, wk, wv, wo, mask,
                                        qb, kb, vb, wqb, wkb, wvb, wob, mfac, nmaskf);

    qkv_gemm<<<dim3(D_ / 128, (B_ * S_) / 128, 3), 256, 0, stream>>>(
        qb, kb, vb, wqb, wkb, wvb, bq, bk, bv, Qp, Kp, Vt, mfac);

    attn_mfma<<<dim3(B_ * H_ * (S_ / 128)), 256, 0, stream>>>(Qp, Kp, Vt, nmaskf, Xc);

    out_gemm<<<dim3(D_ / 64, (B_ * S_) / 128), 256, 0, stream>>>(Xc, wob, bo, (float*)d_out);
}